// Round 8
// baseline (169.662 us; speedup 1.0000x reference)
//
#include <hip/hip_runtime.h>
#include <hip/hip_bf16.h>

// B=8, C=192, N=3136, K=9, COUT=384.
// out[b,o,n] = relu( bias[o] + max_k( u[b,i1,o] + v[b,i0,o] ) )
//   u = (W1-W2)·xs,  v = W2·xs   (per-node GEMMs; 9x less compute than per-edge)
// 3-kernel pipeline:
//   prep_fused: inline-detect dtypes + x->x_T[b][n][200] bf16 + W->A_Tb[j][200] bf16
//   gemm_mfma : T[b][n][768] = x_T · A_Tb^T   (bank-conflict-free granule staging)
//   gather_max: quarter-split gather (1.2MB L2 working set/XCD) + max + bias + relu
// All streaming writes are nontemporal so they don't evict the gather working set.
// ws: flags @0 | A_Tb @1KB (307KB) | x_T @512KB (10.0MB) | T @11MB (38.5MB) ~= 49.5MB

#define Bb   8
#define Cc   192
#define Nn   3136
#define Kk   9
#define CO   384
#define TWOC 384
#define JTOT 768
#define PADC 200   // padded row length (shorts): 400B rows

typedef short  short8 __attribute__((ext_vector_type(8)));
typedef float  f32x4  __attribute__((ext_vector_type(4)));

__device__ __forceinline__ float bf2f(unsigned int u16) {
    union { unsigned int i; float f; } c;
    c.i = u16 << 16;
    return c.f;
}
__device__ __forceinline__ short f2bf(float f) {
    __hip_bfloat16 h = __float2bfloat16(f);
    short s; __builtin_memcpy(&s, &h, 2); return s;
}

// ---------------- K1: fused detect + transpose_x + prep_AT ----------------
__global__ __launch_bounds__(256) void prep_fused(const void* __restrict__ x_,
                                                  const void* __restrict__ W_,
                                                  const int* __restrict__ ei,
                                                  short* __restrict__ xT,
                                                  short* __restrict__ A_Tb,
                                                  int* __restrict__ flags) {
    __shared__ float s[64][33];
    __shared__ int sflag;
    const int tid = threadIdx.x;
    const int bid = blockIdx.x;

    if (tid < 64) {
        unsigned int u = ((const unsigned short*)x_)[2 * tid];
        int bige = (((u >> 7) & 0xFFu) >= 0x88u);   // impossible for N(0,1) bf16
        unsigned long long bf = __ballot(bige);
        int f32 = (bf != 0ull) ? 1 : 0;
        if (tid == 0) sflag = f32;
        if (bid == 0) {
            int oddnz = (ei[2 * tid + 1] != 0);
            unsigned long long bo = __ballot(oddnz);
            if (tid == 0) {
                flags[0] = f32;                      // floats are fp32
                flags[1] = (bo == 0ull) ? 1 : 0;     // indices are int64
            }
        }
    }
    __syncthreads();
    const int fp32 = sflag;

    if (bid < 2352) {
        int b   = bid / 294;              // 294 = 6*49
        int rem = bid - b * 294;
        int ct  = rem / 49;
        int nt  = rem - ct * 49;
        const int n0 = nt * 64;
        const int c0 = ct * 32;
        const int cl   = tid >> 3;
        const int nseg = tid & 7;

        if (fp32) {
            const float* p = (const float*)x_ + ((size_t)b * Cc + c0 + cl) * Nn + n0 + nseg * 8;
            float4 v0 = *(const float4*)p;
            float4 v1 = *(const float4*)(p + 4);
            int nb = nseg * 8;
            s[nb + 0][cl] = v0.x;  s[nb + 1][cl] = v0.y;
            s[nb + 2][cl] = v0.z;  s[nb + 3][cl] = v0.w;
            s[nb + 4][cl] = v1.x;  s[nb + 5][cl] = v1.y;
            s[nb + 6][cl] = v1.z;  s[nb + 7][cl] = v1.w;
        } else {
            const unsigned short* p = (const unsigned short*)x_ + ((size_t)b * Cc + c0 + cl) * Nn + n0 + nseg * 8;
            ushort4 u0 = *(const ushort4*)p;
            ushort4 u1 = *(const ushort4*)(p + 4);
            int nb = nseg * 8;
            s[nb + 0][cl] = bf2f(u0.x);  s[nb + 1][cl] = bf2f(u0.y);
            s[nb + 2][cl] = bf2f(u0.z);  s[nb + 3][cl] = bf2f(u0.w);
            s[nb + 4][cl] = bf2f(u1.x);  s[nb + 5][cl] = bf2f(u1.y);
            s[nb + 6][cl] = bf2f(u1.z);  s[nb + 7][cl] = bf2f(u1.w);
        }
        __syncthreads();

        const int nl = tid >> 2;
        const int cs = tid & 3;
        short8 o;
#pragma unroll
        for (int i = 0; i < 8; ++i) o[i] = f2bf(s[nl][cs * 8 + i]);
        __builtin_nontemporal_store(o, (short8*)(xT + ((size_t)b * Nn + n0 + nl) * PADC + c0 + cs * 8));
    } else {
        int t = (bid - 2352) * 256 + tid;        // 0..147455 exactly
        int j = t / Cc;
        int c = t - j * Cc;
        int row = (j < CO) ? j : (j - CO);
        float w1, w2;
        if (fp32) {
            const float* W = (const float*)W_;
            w1 = W[row * TWOC + c];  w2 = W[row * TWOC + Cc + c];
        } else {
            const unsigned short* W = (const unsigned short*)W_;
            w1 = bf2f(W[row * TWOC + c]);  w2 = bf2f(W[row * TWOC + Cc + c]);
        }
        A_Tb[(size_t)j * PADC + c] = f2bf((j < CO) ? (w1 - w2) : w2);
    }
}

// ---------------- K2: MFMA GEMM: T[b][n][j] = sum_c x_T[b][n][c] * A_Tb[j][c] ----------------
#define MT 64
#define NT 256
#define KT 32
#define LPAD 40

__global__ __launch_bounds__(256) void gemm_mfma(const short* __restrict__ xT,
                                                 const short* __restrict__ A_Tb,
                                                 short* __restrict__ T) {
    __shared__ short Asl[MT * LPAD];   // 5,120 B
    __shared__ short Bsl[NT * LPAD];   // 20,480 B

    const int n0 = blockIdx.x * MT;
    const int j0 = blockIdx.y * NT;
    const int b  = blockIdx.z;
    const int tid  = threadIdx.x;
    const int w    = tid >> 6;
    const int lane = tid & 63;
    const int col  = lane & 15;
    const int quad = lane >> 4;

    f32x4 acc[4][4];
#pragma unroll
    for (int i = 0; i < 4; ++i)
#pragma unroll
        for (int jf = 0; jf < 4; ++jf) acc[i][jf] = (f32x4)(0.0f);

    const int ar = tid >> 2;
    const int ag = tid & 3;

    for (int c0 = 0; c0 < Cc; c0 += KT) {
        *(short8*)(Asl + ar * LPAD + ag * 8) =
            *(const short8*)(xT + ((size_t)b * Nn + n0 + ar) * PADC + c0 + ag * 8);
#pragma unroll
        for (int h = 0; h < 4; ++h) {
            int row = h * 64 + ar;
            *(short8*)(Bsl + row * LPAD + ag * 8) =
                *(const short8*)(A_Tb + (size_t)(j0 + row) * PADC + c0 + ag * 8);
        }
        __syncthreads();

        short8 bf[4];
#pragma unroll
        for (int jf = 0; jf < 4; ++jf)
            bf[jf] = *(const short8*)(&Bsl[(w * 64 + jf * 16 + col) * LPAD + quad * 8]);
#pragma unroll
        for (int fm = 0; fm < 4; ++fm) {
            short8 a = *(const short8*)(&Asl[(fm * 16 + col) * LPAD + quad * 8]);
#pragma unroll
            for (int jf = 0; jf < 4; ++jf)
                acc[fm][jf] = __builtin_amdgcn_mfma_f32_16x16x32_bf16(a, bf[jf], acc[fm][jf], 0, 0, 0);
        }
        __syncthreads();
    }

    const int jbase = j0 + w * 64;
#pragma unroll
    for (int fn = 0; fn < 4; ++fn) {
        int j = jbase + fn * 16 + col;
#pragma unroll
        for (int fm = 0; fm < 4; ++fm) {
#pragma unroll
            for (int r = 0; r < 4; ++r) {
                int n = n0 + fm * 16 + quad * 4 + r;
                __builtin_nontemporal_store(f2bf(acc[fm][fn][r]),
                                            T + ((size_t)(b * Nn + n)) * JTOT + j);
            }
        }
    }
}

// ---------------- K3: gather + max + bias + relu (quarter-split for L2 residency) ----------------
// bid = b + 8*(tile + 98*quarter); working set per (b,quarter) = 2x0.6MB = 1.2MB << 4MB L2.
// Output stores nontemporal so the stream doesn't evict gathered T rows.
__global__ __launch_bounds__(384) void gather_max(const int* __restrict__ ei,
                                                  const short* __restrict__ T,
                                                  const void* __restrict__ bias_,
                                                  void* __restrict__ out_,
                                                  const int* __restrict__ flags) {
    __shared__ float sm[32][97];     // [node][local channel], pad 97: column reads conflict-free
    __shared__ int si0[32][Kk];
    __shared__ int si1[32][Kk];

    const int fp32 = flags[0];
    const int is64 = flags[1];
    const int bid  = blockIdx.x;
    const int b    = bid & 7;
    const int rest = bid >> 3;        // 0..391
    const int quarter = rest / 98;    // 0..3
    const int n0   = (rest % 98) * 32;
    const int tid  = threadIdx.x;

    for (int s = tid; s < 32 * 2 * Kk; s += 384) {
        int ln = s / (2 * Kk);
        int slot = s - ln * (2 * Kk);
        int n = n0 + ln;
        size_t pos; int* dstp;
        if (slot < Kk) { pos = ((size_t)b * Nn + n) * Kk + slot;               dstp = &si0[ln][slot]; }
        else           { pos = ((size_t)(Bb + b) * Nn + n) * Kk + (slot - Kk); dstp = &si1[ln][slot - Kk]; }
        int v = is64 ? ei[2 * pos] : ei[pos];
        *dstp = (v < 0) ? 0 : (v >= Nn ? Nn - 1 : v);
    }
    __syncthreads();

    // phase 1: thread (cg, seg): 4 channels (8B), 2 nodes
    const int cg  = tid % 24;               // channel group of 4 within quarter
    const int seg = tid / 24;               // 0..15 -> nodes seg*2, seg*2+1
    const int och = quarter * 96 + cg * 4;  // global channel base
    const unsigned short* Tb = (const unsigned short*)T + (size_t)b * Nn * JTOT;

    float b0, b1, b2, b3;
    if (fp32) {
        const float* bp = (const float*)bias_ + och;
        b0 = bp[0]; b1 = bp[1]; b2 = bp[2]; b3 = bp[3];
    } else {
        const unsigned short* bp = (const unsigned short*)bias_ + och;
        b0 = bf2f(bp[0]); b1 = bf2f(bp[1]); b2 = bf2f(bp[2]); b3 = bf2f(bp[3]);
    }

#pragma unroll
    for (int t = 0; t < 2; ++t) {
        int ln = seg * 2 + t;
        float m0 = -INFINITY, m1 = -INFINITY, m2 = -INFINITY, m3 = -INFINITY;
#pragma unroll
        for (int k = 0; k < Kk; ++k) {
            uint2 uu = *(const uint2*)(Tb + (size_t)si1[ln][k] * JTOT + och);
            uint2 vv = *(const uint2*)(Tb + (size_t)si0[ln][k] * JTOT + CO + och);
            m0 = fmaxf(m0, bf2f(uu.x & 0xffffu) + bf2f(vv.x & 0xffffu));
            m1 = fmaxf(m1, bf2f(uu.x >> 16)     + bf2f(vv.x >> 16));
            m2 = fmaxf(m2, bf2f(uu.y & 0xffffu) + bf2f(vv.y & 0xffffu));
            m3 = fmaxf(m3, bf2f(uu.y >> 16)     + bf2f(vv.y >> 16));
        }
        float4 r = make_float4(fmaxf(m0 + b0, 0.0f), fmaxf(m1 + b1, 0.0f),
                               fmaxf(m2 + b2, 0.0f), fmaxf(m3 + b3, 0.0f));
        *(float4*)&sm[ln][cg * 4] = r;
    }
    __syncthreads();

    // phase 2: transposed, coalesced, nontemporal writes; 12 groups x 8 rows x 32 lanes
    const int g = tid >> 5, l = tid & 31;
    if (fp32) {
        float* op = (float*)out_;
#pragma unroll
        for (int rr = 0; rr < 8; ++rr) {
            int ol = g * 8 + rr;
            int o  = quarter * 96 + ol;
            __builtin_nontemporal_store(sm[l][ol], op + ((size_t)b * CO + o) * Nn + n0 + l);
        }
    } else {
        unsigned short* op = (unsigned short*)out_;
#pragma unroll
        for (int rr = 0; rr < 8; ++rr) {
            int ol = g * 8 + rr;
            int o  = quarter * 96 + ol;
            __builtin_nontemporal_store((unsigned short)f2bf(sm[l][ol]),
                                        op + ((size_t)b * CO + o) * Nn + n0 + l);
        }
    }
}

extern "C" void kernel_launch(void* const* d_in, const int* in_sizes, int n_in,
                              void* d_out, int out_size, void* d_ws, size_t ws_size,
                              hipStream_t stream) {
    const void* x  = d_in[0];
    const int*  ei = (const int*)d_in[1];
    const void* W  = d_in[2];
    const void* bs = d_in[3];

    char* ws = (char*)d_ws;
    int*   flags = (int*)ws;                               // 64 B
    short* A_Tb  = (short*)(ws + 1024);                    // 768*200*2 = 307,200 B
    short* xT    = (short*)(ws + (512u << 10));            // 8*3136*200*2 = 10,035,200 B
    short* T     = (short*)(ws + (11u << 20));             // 8*3136*768*2 = 38,535,168 B

    prep_fused<<<2352 + 576, 256, 0, stream>>>(x, W, ei, xT, A_Tb, flags);

    dim3 g1(Nn / MT, JTOT / NT, Bb);   // (49, 3, 8)
    gemm_mfma<<<g1, 256, 0, stream>>>(xT, A_Tb, T);

    gather_max<<<Bb * 4 * (Nn / 32), 384, 0, stream>>>(ei, T, bs, d_out, flags);
}

// Round 9
// 133.266 us; speedup vs baseline: 1.2731x; 1.2731x over previous
//
#include <hip/hip_runtime.h>
#include <hip/hip_bf16.h>

// B=8, C=192, N=3136, K=9, COUT=384.
// out[b,o,n] = relu( bias[o] + max_k( u[b,i1,o] + v[b,i0,o] ) )
//   u = (W1-W2)·xs,  v = W2·xs   (per-node GEMMs; 9x less compute than per-edge)
// 3-kernel pipeline:
//   prep_fused: inline-detect dtypes + x->x_T[b][n][200] bf16 + W->A_Tb[j][200] bf16
//   gemm_mfma : T[b][n][768]; SINGLE-SHOT K=192 (one barrier), 64n x 64j tiles,
//               C routed through LDS for full-line coalesced writes
//   gather_max: half-split gather + max + bias + relu, coalesced transposed writes
// ws: flags @0 | A_Tb @1KB (307KB) | x_T @512KB (10.0MB) | T @11MB (38.5MB) ~= 49.5MB

#define Bb   8
#define Cc   192
#define Nn   3136
#define Kk   9
#define CO   384
#define TWOC 384
#define JTOT 768
#define PADC 200   // padded row length (shorts): 400B rows

typedef short  short8 __attribute__((ext_vector_type(8)));
typedef float  f32x4  __attribute__((ext_vector_type(4)));

__device__ __forceinline__ float bf2f(unsigned int u16) {
    union { unsigned int i; float f; } c;
    c.i = u16 << 16;
    return c.f;
}
__device__ __forceinline__ short f2bf(float f) {
    __hip_bfloat16 h = __float2bfloat16(f);
    short s; __builtin_memcpy(&s, &h, 2); return s;
}

// ---------------- K1: fused detect + transpose_x + prep_AT ----------------
__global__ __launch_bounds__(256) void prep_fused(const void* __restrict__ x_,
                                                  const void* __restrict__ W_,
                                                  const int* __restrict__ ei,
                                                  short* __restrict__ xT,
                                                  short* __restrict__ A_Tb,
                                                  int* __restrict__ flags) {
    __shared__ float s[64][33];
    __shared__ int sflag;
    const int tid = threadIdx.x;
    const int bid = blockIdx.x;

    if (tid < 64) {
        unsigned int u = ((const unsigned short*)x_)[2 * tid];
        int bige = (((u >> 7) & 0xFFu) >= 0x88u);   // impossible for N(0,1) bf16
        unsigned long long bf = __ballot(bige);
        int f32 = (bf != 0ull) ? 1 : 0;
        if (tid == 0) sflag = f32;
        if (bid == 0) {
            int oddnz = (ei[2 * tid + 1] != 0);
            unsigned long long bo = __ballot(oddnz);
            if (tid == 0) {
                flags[0] = f32;                      // floats are fp32
                flags[1] = (bo == 0ull) ? 1 : 0;     // indices are int64
            }
        }
    }
    __syncthreads();
    const int fp32 = sflag;

    if (bid < 2352) {
        int b   = bid / 294;              // 294 = 6*49
        int rem = bid - b * 294;
        int ct  = rem / 49;
        int nt  = rem - ct * 49;
        const int n0 = nt * 64;
        const int c0 = ct * 32;
        const int cl   = tid >> 3;
        const int nseg = tid & 7;

        if (fp32) {
            const float* p = (const float*)x_ + ((size_t)b * Cc + c0 + cl) * Nn + n0 + nseg * 8;
            float4 v0 = *(const float4*)p;
            float4 v1 = *(const float4*)(p + 4);
            int nb = nseg * 8;
            s[nb + 0][cl] = v0.x;  s[nb + 1][cl] = v0.y;
            s[nb + 2][cl] = v0.z;  s[nb + 3][cl] = v0.w;
            s[nb + 4][cl] = v1.x;  s[nb + 5][cl] = v1.y;
            s[nb + 6][cl] = v1.z;  s[nb + 7][cl] = v1.w;
        } else {
            const unsigned short* p = (const unsigned short*)x_ + ((size_t)b * Cc + c0 + cl) * Nn + n0 + nseg * 8;
            ushort4 u0 = *(const ushort4*)p;
            ushort4 u1 = *(const ushort4*)(p + 4);
            int nb = nseg * 8;
            s[nb + 0][cl] = bf2f(u0.x);  s[nb + 1][cl] = bf2f(u0.y);
            s[nb + 2][cl] = bf2f(u0.z);  s[nb + 3][cl] = bf2f(u0.w);
            s[nb + 4][cl] = bf2f(u1.x);  s[nb + 5][cl] = bf2f(u1.y);
            s[nb + 6][cl] = bf2f(u1.z);  s[nb + 7][cl] = bf2f(u1.w);
        }
        __syncthreads();

        const int nl = tid >> 2;
        const int cs = tid & 3;
        short8 o;
#pragma unroll
        for (int i = 0; i < 8; ++i) o[i] = f2bf(s[nl][cs * 8 + i]);
        *(short8*)(xT + ((size_t)b * Nn + n0 + nl) * PADC + c0 + cs * 8) = o;
    } else {
        int t = (bid - 2352) * 256 + tid;        // 0..147455 exactly
        int j = t / Cc;
        int c = t - j * Cc;
        int row = (j < CO) ? j : (j - CO);
        float w1, w2;
        if (fp32) {
            const float* W = (const float*)W_;
            w1 = W[row * TWOC + c];  w2 = W[row * TWOC + Cc + c];
        } else {
            const unsigned short* W = (const unsigned short*)W_;
            w1 = bf2f(W[row * TWOC + c]);  w2 = bf2f(W[row * TWOC + Cc + c]);
        }
        A_Tb[(size_t)j * PADC + c] = f2bf((j < CO) ? (w1 - w2) : w2);
    }
}

// ---------------- K2: MFMA GEMM, single-shot K=192 ----------------
// tile 64(n) x 64(j); wave w covers j [w*16, w*16+16). One barrier for staging,
// then 24 MFMAs/wave uninterrupted. C goes through LDS for full-line stores.
__global__ __launch_bounds__(256) void gemm_mfma(const short* __restrict__ xT,
                                                 const short* __restrict__ A_Tb,
                                                 short* __restrict__ T) {
    __shared__ short Asl[64 * PADC];   // 25,600 B  [n][c]
    __shared__ short Bsl[64 * PADC];   // 25,600 B  [j][c]
    // C-transpose tile reuses Asl after compute: 64 x 72 shorts = 9,216 B

    const int n0 = blockIdx.x * 64;
    const int j0 = blockIdx.y * 64;
    const int b  = blockIdx.z;
    const int tid  = threadIdx.x;
    const int w    = tid >> 6;
    const int lane = tid & 63;
    const int col  = lane & 15;
    const int quad = lane >> 4;

    // ---- stage both tiles: 1536 granules (16B) each, 6 per thread ----
#pragma unroll
    for (int i = 0; i < 6; ++i) {
        int g   = tid + i * 256;
        int row = g / 24;
        int pos = g - row * 24;
        *(short8*)(Asl + row * PADC + pos * 8) =
            *(const short8*)(xT + ((size_t)b * Nn + n0 + row) * PADC + pos * 8);
        *(short8*)(Bsl + row * PADC + pos * 8) =
            *(const short8*)(A_Tb + (size_t)(j0 + row) * PADC + pos * 8);
    }
    __syncthreads();

    // ---- compute: A[m=lane&15][k=quad*8+i], B rows = j, D[row=quad*4+r][col=lane&15] ----
    f32x4 acc[4];
#pragma unroll
    for (int i = 0; i < 4; ++i) acc[i] = (f32x4)(0.0f);

#pragma unroll
    for (int kf = 0; kf < 6; ++kf) {
        short8 bfr = *(const short8*)(Bsl + (w * 16 + col) * PADC + kf * 32 + quad * 8);
#pragma unroll
        for (int fm = 0; fm < 4; ++fm) {
            short8 a = *(const short8*)(Asl + (fm * 16 + col) * PADC + kf * 32 + quad * 8);
            acc[fm] = __builtin_amdgcn_mfma_f32_16x16x32_bf16(a, bfr, acc[fm], 0, 0, 0);
        }
    }
    __syncthreads();   // all LDS reads done; reuse Asl as C-tile

    // ---- epilogue: acc -> LDS [64n][72] -> full-line coalesced global stores ----
    short* Ct = Asl;
#pragma unroll
    for (int fm = 0; fm < 4; ++fm) {
#pragma unroll
        for (int r = 0; r < 4; ++r) {
            Ct[(fm * 16 + quad * 4 + r) * 72 + w * 16 + col] = f2bf(acc[fm][r]);
        }
    }
    __syncthreads();

    {
        const int row = tid >> 2;        // 0..63
        const int gq  = tid & 3;         // 4 threads/row, 2 granules each
#pragma unroll
        for (int i = 0; i < 2; ++i) {
            int g = gq + i * 4;          // granule of 8 shorts; lanes 0-3 -> 64B contiguous
            *(short8*)(T + ((size_t)(b * Nn + n0 + row)) * JTOT + j0 + g * 8) =
                *(const short8*)(Ct + row * 72 + g * 8);
        }
    }
}

// ---------------- K3: gather + max + bias + relu (half-split for L2 residency) ----------------
__global__ __launch_bounds__(384) void gather_max(const int* __restrict__ ei,
                                                  const short* __restrict__ T,
                                                  const void* __restrict__ bias_,
                                                  void* __restrict__ out_,
                                                  const int* __restrict__ flags) {
    __shared__ float sm[32][193];
    __shared__ int si0[32][Kk];
    __shared__ int si1[32][Kk];

    const int fp32 = flags[0];
    const int is64 = flags[1];
    const int bid  = blockIdx.x;
    const int b    = bid & 7;
    const int rest = bid >> 3;        // 0..195
    const int half = rest / 98;       // 0,1
    const int n0   = (rest % 98) * 32;
    const int tid  = threadIdx.x;

    for (int s = tid; s < 32 * 2 * Kk; s += 384) {
        int ln = s / (2 * Kk);
        int slot = s - ln * (2 * Kk);
        int n = n0 + ln;
        size_t pos; int* dstp;
        if (slot < Kk) { pos = ((size_t)b * Nn + n) * Kk + slot;               dstp = &si0[ln][slot]; }
        else           { pos = ((size_t)(Bb + b) * Nn + n) * Kk + (slot - Kk); dstp = &si1[ln][slot - Kk]; }
        int v = is64 ? ei[2 * pos] : ei[pos];
        *dstp = (v < 0) ? 0 : (v >= Nn ? Nn - 1 : v);
    }
    __syncthreads();

    // phase 1: thread (cg, seg): 4 channels (8B loads), 4 nodes
    const int cg  = tid % 48;               // channel group of 4 within half
    const int seg = tid / 48;               // 0..7 -> nodes seg*4 .. seg*4+3
    const int och = half * 192 + cg * 4;
    const unsigned short* Tb = (const unsigned short*)T + (size_t)b * Nn * JTOT;

    float b0, b1, b2, b3;
    if (fp32) {
        const float* bp = (const float*)bias_ + och;
        b0 = bp[0]; b1 = bp[1]; b2 = bp[2]; b3 = bp[3];
    } else {
        const unsigned short* bp = (const unsigned short*)bias_ + och;
        b0 = bf2f(bp[0]); b1 = bf2f(bp[1]); b2 = bf2f(bp[2]); b3 = bf2f(bp[3]);
    }

#pragma unroll
    for (int t = 0; t < 4; ++t) {
        int ln = seg * 4 + t;
        float m0 = -INFINITY, m1 = -INFINITY, m2 = -INFINITY, m3 = -INFINITY;
#pragma unroll
        for (int k = 0; k < Kk; ++k) {
            uint2 uu = *(const uint2*)(Tb + (size_t)si1[ln][k] * JTOT + och);
            uint2 vv = *(const uint2*)(Tb + (size_t)si0[ln][k] * JTOT + CO + och);
            m0 = fmaxf(m0, bf2f(uu.x & 0xffffu) + bf2f(vv.x & 0xffffu));
            m1 = fmaxf(m1, bf2f(uu.x >> 16)     + bf2f(vv.x >> 16));
            m2 = fmaxf(m2, bf2f(uu.y & 0xffffu) + bf2f(vv.y & 0xffffu));
            m3 = fmaxf(m3, bf2f(uu.y >> 16)     + bf2f(vv.y >> 16));
        }
        sm[ln][cg * 4 + 0] = fmaxf(m0 + b0, 0.0f);
        sm[ln][cg * 4 + 1] = fmaxf(m1 + b1, 0.0f);
        sm[ln][cg * 4 + 2] = fmaxf(m2 + b2, 0.0f);
        sm[ln][cg * 4 + 3] = fmaxf(m3 + b3, 0.0f);
    }
    __syncthreads();

    // phase 2: transposed coalesced writes; 12 groups x 16 rows x 32 lanes
    const int g = tid >> 5, l = tid & 31;
    if (fp32) {
        float* op = (float*)out_;
#pragma unroll
        for (int rr = 0; rr < 16; ++rr) {
            int ol = g * 16 + rr;
            int o  = half * 192 + ol;
            op[((size_t)b * CO + o) * Nn + n0 + l] = sm[l][ol];
        }
    } else {
        __hip_bfloat16* op = (__hip_bfloat16*)out_;
#pragma unroll
        for (int rr = 0; rr < 16; ++rr) {
            int ol = g * 16 + rr;
            int o  = half * 192 + ol;
            op[((size_t)b * CO + o) * Nn + n0 + l] = __float2bfloat16(sm[l][ol]);
        }
    }
}

extern "C" void kernel_launch(void* const* d_in, const int* in_sizes, int n_in,
                              void* d_out, int out_size, void* d_ws, size_t ws_size,
                              hipStream_t stream) {
    const void* x  = d_in[0];
    const int*  ei = (const int*)d_in[1];
    const void* W  = d_in[2];
    const void* bs = d_in[3];

    char* ws = (char*)d_ws;
    int*   flags = (int*)ws;                               // 64 B
    short* A_Tb  = (short*)(ws + 1024);                    // 768*200*2 = 307,200 B
    short* xT    = (short*)(ws + (512u << 10));            // 8*3136*200*2 = 10,035,200 B
    short* T     = (short*)(ws + (11u << 20));             // 8*3136*768*2 = 38,535,168 B

    prep_fused<<<2352 + 576, 256, 0, stream>>>(x, W, ei, xT, A_Tb, flags);

    dim3 g1(Nn / 64, JTOT / 64, Bb);   // (49, 12, 8) = 4704 blocks
    gemm_mfma<<<g1, 256, 0, stream>>>(xT, A_Tb, T);

    gather_max<<<Bb * 2 * (Nn / 32), 384, 0, stream>>>(ei, T, bs, d_out, flags);
}

// Round 10
// 132.663 us; speedup vs baseline: 1.2789x; 1.0045x over previous
//
#include <hip/hip_runtime.h>
#include <hip/hip_bf16.h>

// B=8, C=192, N=3136, K=9, COUT=384.
// out[b,o,n] = relu( bias[o] + max_k( u[b,i1,o] + v[b,i0,o] ) )
//   u = (W1-W2)·xs,  v = W2·xs   (per-node GEMMs; 9x less compute than per-edge)
// 3-kernel pipeline:
//   prep_fused: inline-detect dtypes + x->x_T[b][n][200] bf16 + W->A_Tb[j][200] bf16
//   gemm_mfma : T[b][n][768]; single-shot K=192 (one staging barrier), 64n x 64j,
//               C routed through LDS for full-line coalesced writes
//   gather_max: QUARTER-split gather (1.2MB working set per (b,quarter) < 4MB L2/XCD)
// ws: flags @0 | A_Tb @1KB (307KB) | x_T @512KB (10.0MB) | T @11MB (38.5MB) ~= 49.5MB

#define Bb   8
#define Cc   192
#define Nn   3136
#define Kk   9
#define CO   384
#define TWOC 384
#define JTOT 768
#define PADC 200   // padded row length (shorts): 400B rows

typedef short  short8 __attribute__((ext_vector_type(8)));
typedef float  f32x4  __attribute__((ext_vector_type(4)));

__device__ __forceinline__ float bf2f(unsigned int u16) {
    union { unsigned int i; float f; } c;
    c.i = u16 << 16;
    return c.f;
}
__device__ __forceinline__ short f2bf(float f) {
    __hip_bfloat16 h = __float2bfloat16(f);
    short s; __builtin_memcpy(&s, &h, 2); return s;
}

// ---------------- K1: fused detect + transpose_x + prep_AT ----------------
__global__ __launch_bounds__(256) void prep_fused(const void* __restrict__ x_,
                                                  const void* __restrict__ W_,
                                                  const int* __restrict__ ei,
                                                  short* __restrict__ xT,
                                                  short* __restrict__ A_Tb,
                                                  int* __restrict__ flags) {
    __shared__ float s[64][33];
    __shared__ int sflag;
    const int tid = threadIdx.x;
    const int bid = blockIdx.x;

    if (tid < 64) {
        unsigned int u = ((const unsigned short*)x_)[2 * tid];
        int bige = (((u >> 7) & 0xFFu) >= 0x88u);   // impossible for N(0,1) bf16
        unsigned long long bf = __ballot(bige);
        int f32 = (bf != 0ull) ? 1 : 0;
        if (tid == 0) sflag = f32;
        if (bid == 0) {
            int oddnz = (ei[2 * tid + 1] != 0);
            unsigned long long bo = __ballot(oddnz);
            if (tid == 0) {
                flags[0] = f32;                      // floats are fp32
                flags[1] = (bo == 0ull) ? 1 : 0;     // indices are int64
            }
        }
    }
    __syncthreads();
    const int fp32 = sflag;

    if (bid < 2352) {
        int b   = bid / 294;              // 294 = 6*49
        int rem = bid - b * 294;
        int ct  = rem / 49;
        int nt  = rem - ct * 49;
        const int n0 = nt * 64;
        const int c0 = ct * 32;
        const int cl   = tid >> 3;
        const int nseg = tid & 7;

        if (fp32) {
            const float* p = (const float*)x_ + ((size_t)b * Cc + c0 + cl) * Nn + n0 + nseg * 8;
            float4 v0 = *(const float4*)p;
            float4 v1 = *(const float4*)(p + 4);
            int nb = nseg * 8;
            s[nb + 0][cl] = v0.x;  s[nb + 1][cl] = v0.y;
            s[nb + 2][cl] = v0.z;  s[nb + 3][cl] = v0.w;
            s[nb + 4][cl] = v1.x;  s[nb + 5][cl] = v1.y;
            s[nb + 6][cl] = v1.z;  s[nb + 7][cl] = v1.w;
        } else {
            const unsigned short* p = (const unsigned short*)x_ + ((size_t)b * Cc + c0 + cl) * Nn + n0 + nseg * 8;
            ushort4 u0 = *(const ushort4*)p;
            ushort4 u1 = *(const ushort4*)(p + 4);
            int nb = nseg * 8;
            s[nb + 0][cl] = bf2f(u0.x);  s[nb + 1][cl] = bf2f(u0.y);
            s[nb + 2][cl] = bf2f(u0.z);  s[nb + 3][cl] = bf2f(u0.w);
            s[nb + 4][cl] = bf2f(u1.x);  s[nb + 5][cl] = bf2f(u1.y);
            s[nb + 6][cl] = bf2f(u1.z);  s[nb + 7][cl] = bf2f(u1.w);
        }
        __syncthreads();

        const int nl = tid >> 2;
        const int cs = tid & 3;
        short8 o;
#pragma unroll
        for (int i = 0; i < 8; ++i) o[i] = f2bf(s[nl][cs * 8 + i]);
        *(short8*)(xT + ((size_t)b * Nn + n0 + nl) * PADC + c0 + cs * 8) = o;
    } else {
        int t = (bid - 2352) * 256 + tid;        // 0..147455 exactly
        int j = t / Cc;
        int c = t - j * Cc;
        int row = (j < CO) ? j : (j - CO);
        float w1, w2;
        if (fp32) {
            const float* W = (const float*)W_;
            w1 = W[row * TWOC + c];  w2 = W[row * TWOC + Cc + c];
        } else {
            const unsigned short* W = (const unsigned short*)W_;
            w1 = bf2f(W[row * TWOC + c]);  w2 = bf2f(W[row * TWOC + Cc + c]);
        }
        A_Tb[(size_t)j * PADC + c] = f2bf((j < CO) ? (w1 - w2) : w2);
    }
}

// ---------------- K2: MFMA GEMM, single-shot K=192 ----------------
__global__ __launch_bounds__(256) void gemm_mfma(const short* __restrict__ xT,
                                                 const short* __restrict__ A_Tb,
                                                 short* __restrict__ T) {
    __shared__ short Asl[64 * PADC];   // 25,600 B  [n][c]
    __shared__ short Bsl[64 * PADC];   // 25,600 B  [j][c]

    const int n0 = blockIdx.x * 64;
    const int j0 = blockIdx.y * 64;
    const int b  = blockIdx.z;
    const int tid  = threadIdx.x;
    const int w    = tid >> 6;
    const int lane = tid & 63;
    const int col  = lane & 15;
    const int quad = lane >> 4;

    // stage both tiles: 1536 granules (16B) each, 6 per thread
#pragma unroll
    for (int i = 0; i < 6; ++i) {
        int g   = tid + i * 256;
        int row = g / 24;
        int pos = g - row * 24;
        *(short8*)(Asl + row * PADC + pos * 8) =
            *(const short8*)(xT + ((size_t)b * Nn + n0 + row) * PADC + pos * 8);
        *(short8*)(Bsl + row * PADC + pos * 8) =
            *(const short8*)(A_Tb + (size_t)(j0 + row) * PADC + pos * 8);
    }
    __syncthreads();

    f32x4 acc[4];
#pragma unroll
    for (int i = 0; i < 4; ++i) acc[i] = (f32x4)(0.0f);

#pragma unroll
    for (int kf = 0; kf < 6; ++kf) {
        short8 bfr = *(const short8*)(Bsl + (w * 16 + col) * PADC + kf * 32 + quad * 8);
#pragma unroll
        for (int fm = 0; fm < 4; ++fm) {
            short8 a = *(const short8*)(Asl + (fm * 16 + col) * PADC + kf * 32 + quad * 8);
            acc[fm] = __builtin_amdgcn_mfma_f32_16x16x32_bf16(a, bfr, acc[fm], 0, 0, 0);
        }
    }
    __syncthreads();   // all LDS reads done; reuse Asl as C-tile

    // epilogue: acc -> LDS [64n][72] -> full-line coalesced global stores
    short* Ct = Asl;
#pragma unroll
    for (int fm = 0; fm < 4; ++fm) {
#pragma unroll
        for (int r = 0; r < 4; ++r) {
            Ct[(fm * 16 + quad * 4 + r) * 72 + w * 16 + col] = f2bf(acc[fm][r]);
        }
    }
    __syncthreads();

    {
        const int row = tid >> 2;        // 0..63
        const int gq  = tid & 3;
#pragma unroll
        for (int i = 0; i < 2; ++i) {
            int g = gq + i * 4;
            *(short8*)(T + ((size_t)(b * Nn + n0 + row)) * JTOT + j0 + g * 8) =
                *(const short8*)(Ct + row * 72 + g * 8);
        }
    }
}

// ---------------- K3: gather + max + bias + relu (quarter-split for L2 residency) ----------------
// bid = b + 8*(tile + 98*quarter); working set per (b,quarter) = 2 x 0.6MB = 1.2MB << 4MB L2.
__global__ __launch_bounds__(384) void gather_max(const int* __restrict__ ei,
                                                  const short* __restrict__ T,
                                                  const void* __restrict__ bias_,
                                                  void* __restrict__ out_,
                                                  const int* __restrict__ flags) {
    __shared__ float sm[32][97];     // [node][local channel], pad 97
    __shared__ int si0[32][Kk];
    __shared__ int si1[32][Kk];

    const int fp32 = flags[0];
    const int is64 = flags[1];
    const int bid  = blockIdx.x;
    const int b    = bid & 7;
    const int rest = bid >> 3;        // 0..391
    const int quarter = rest / 98;    // 0..3
    const int n0   = (rest % 98) * 32;
    const int tid  = threadIdx.x;

    for (int s = tid; s < 32 * 2 * Kk; s += 384) {
        int ln = s / (2 * Kk);
        int slot = s - ln * (2 * Kk);
        int n = n0 + ln;
        size_t pos; int* dstp;
        if (slot < Kk) { pos = ((size_t)b * Nn + n) * Kk + slot;               dstp = &si0[ln][slot]; }
        else           { pos = ((size_t)(Bb + b) * Nn + n) * Kk + (slot - Kk); dstp = &si1[ln][slot - Kk]; }
        int v = is64 ? ei[2 * pos] : ei[pos];
        *dstp = (v < 0) ? 0 : (v >= Nn ? Nn - 1 : v);
    }
    __syncthreads();

    // phase 1: thread (cg, seg): 4 channels (8B loads), 2 nodes
    const int cg  = tid % 24;               // channel group of 4 within quarter
    const int seg = tid / 24;               // 0..15 -> nodes seg*2, seg*2+1
    const int och = quarter * 96 + cg * 4;
    const unsigned short* Tb = (const unsigned short*)T + (size_t)b * Nn * JTOT;

    float b0, b1, b2, b3;
    if (fp32) {
        const float* bp = (const float*)bias_ + och;
        b0 = bp[0]; b1 = bp[1]; b2 = bp[2]; b3 = bp[3];
    } else {
        const unsigned short* bp = (const unsigned short*)bias_ + och;
        b0 = bf2f(bp[0]); b1 = bf2f(bp[1]); b2 = bf2f(bp[2]); b3 = bf2f(bp[3]);
    }

#pragma unroll
    for (int t = 0; t < 2; ++t) {
        int ln = seg * 2 + t;
        float m0 = -INFINITY, m1 = -INFINITY, m2 = -INFINITY, m3 = -INFINITY;
#pragma unroll
        for (int k = 0; k < Kk; ++k) {
            uint2 uu = *(const uint2*)(Tb + (size_t)si1[ln][k] * JTOT + och);
            uint2 vv = *(const uint2*)(Tb + (size_t)si0[ln][k] * JTOT + CO + och);
            m0 = fmaxf(m0, bf2f(uu.x & 0xffffu) + bf2f(vv.x & 0xffffu));
            m1 = fmaxf(m1, bf2f(uu.x >> 16)     + bf2f(vv.x >> 16));
            m2 = fmaxf(m2, bf2f(uu.y & 0xffffu) + bf2f(vv.y & 0xffffu));
            m3 = fmaxf(m3, bf2f(uu.y >> 16)     + bf2f(vv.y >> 16));
        }
        sm[ln][cg * 4 + 0] = fmaxf(m0 + b0, 0.0f);
        sm[ln][cg * 4 + 1] = fmaxf(m1 + b1, 0.0f);
        sm[ln][cg * 4 + 2] = fmaxf(m2 + b2, 0.0f);
        sm[ln][cg * 4 + 3] = fmaxf(m3 + b3, 0.0f);
    }
    __syncthreads();

    // phase 2: transposed coalesced writes; 12 groups x 8 rows x 32 lanes
    const int g = tid >> 5, l = tid & 31;
    if (fp32) {
        float* op = (float*)out_;
#pragma unroll
        for (int rr = 0; rr < 8; ++rr) {
            int ol = g * 8 + rr;
            int o  = quarter * 96 + ol;
            op[((size_t)b * CO + o) * Nn + n0 + l] = sm[l][ol];
        }
    } else {
        __hip_bfloat16* op = (__hip_bfloat16*)out_;
#pragma unroll
        for (int rr = 0; rr < 8; ++rr) {
            int ol = g * 8 + rr;
            int o  = quarter * 96 + ol;
            op[((size_t)b * CO + o) * Nn + n0 + l] = __float2bfloat16(sm[l][ol]);
        }
    }
}

extern "C" void kernel_launch(void* const* d_in, const int* in_sizes, int n_in,
                              void* d_out, int out_size, void* d_ws, size_t ws_size,
                              hipStream_t stream) {
    const void* x  = d_in[0];
    const int*  ei = (const int*)d_in[1];
    const void* W  = d_in[2];
    const void* bs = d_in[3];

    char* ws = (char*)d_ws;
    int*   flags = (int*)ws;                               // 64 B
    short* A_Tb  = (short*)(ws + 1024);                    // 768*200*2 = 307,200 B
    short* xT    = (short*)(ws + (512u << 10));            // 8*3136*200*2 = 10,035,200 B
    short* T     = (short*)(ws + (11u << 20));             // 8*3136*768*2 = 38,535,168 B

    prep_fused<<<2352 + 576, 256, 0, stream>>>(x, W, ei, xT, A_Tb, flags);

    dim3 g1(Nn / 64, JTOT / 64, Bb);   // (49, 12, 8) = 4704 blocks
    gemm_mfma<<<g1, 256, 0, stream>>>(xT, A_Tb, T);

    gather_max<<<Bb * 4 * (Nn / 32), 384, 0, stream>>>(ei, T, bs, d_out, flags);
}